// Round 11
// baseline (114.337 us; speedup 1.0000x reference)
//
#include <hip/hip_runtime.h>
#include <stdint.h>

// Problem constants (from reference): B=4, T=512, S=256, V=50257.
#define DIM_B 4
#define DIM_T 512
#define DIM_S 256
#define DIM_V 50257
#define DEPTH 4            // register patch slots per thread (Poisson(1): P(>4)~0.4%)

// Native clang vector type: __builtin_nontemporal_store requires a pointer to
// integer/float/vector-of-such; HIP's float4 is a struct and is rejected.
typedef float floatx4 __attribute__((ext_vector_type(4)));

// R7's proven single-touch kernel with ONE change: Phase-2 streaming stores are
// NON-TEMPORAL (no L2 allocation). Theory: plain streaming stores allocate
// 412MB of lines in the 32MB L2 -> continuous dirty-eviction storm in TCC that
// throttles the store pipe to ~4.6 TB/s; the vendor fill's no-allocate stores
// avoid it and run 6.8 TB/s. On CDNA 'nt' is a TCC allocation-policy bit (ops
// still flow through TCC in order), so the vmcnt-draining __syncthreads before
// Phase 3 keeps the store->atomicAdd ordering correct.
__global__ __launch_bounds__(256) void onepass_nt_kernel(
    const float* __restrict__ p_pos,   // [B, T, S]
    const int*   __restrict__ src,     // [B, S]  (int64 narrowed to int32)
    float*       __restrict__ out)     // [B, T, V]
{
    __shared__ uint32_t bkey[256][DEPTH];   // middle-local elem offset d
    __shared__ float    bval[256][DEPTH];
    __shared__ int      bcnt[256];
    __shared__ uint32_t okey[DIM_S];        // overflow: row-local elem v
    __shared__ float    oval[DIM_S];
    __shared__ int      ocnt;

    const int row = blockIdx.x;        // row = b*T + t
    const int b   = row >> 9;          // T = 512
    const int tid = threadIdx.x;       // s index (S == blockDim.x == 256)

    bcnt[tid] = 0;
    if (tid == 0) ocnt = 0;
    __syncthreads();

    const long long rb   = (long long)row * DIM_V;
    const int head  = (int)((4 - (row & 3)) & 3);   // 50257 % 4 == 1
    const int nvec  = (DIM_V - head) >> 2;          // 12563 or 12564 chunks
    const int ntail = DIM_V - head - (nvec << 2);   // 0..3

    // ---- Phase 1: route this thread's entry ----
    {
        const int   v = src[b * DIM_S + tid];
        const float p = p_pos[(size_t)row * DIM_S + tid];
        const int   d = v - head;                   // middle-local elem offset
        bool to_ovf = true;
        if (d >= 0 && d < (nvec << 2)) {
            const int c = d >> 2;                   // chunk index
            const int t = c & 255;                  // owning thread
            const int j = atomicAdd(&bcnt[t], 1);
            if (j < DEPTH) { bkey[t][j] = (uint32_t)d; bval[t][j] = p; to_ovf = false; }
        }
        if (to_ovf) {
            const int j = atomicAdd(&ocnt, 1);
            okey[j] = (uint32_t)v; oval[j] = p;
        }
    }
    __syncthreads();

    // ---- pull my register patches (sentinel never matches d <= 50255) ----
    uint32_t k0 = 0xFFFFFFFFu, k1 = 0xFFFFFFFFu, k2 = 0xFFFFFFFFu, k3 = 0xFFFFFFFFu;
    float    v0 = 0.0f, v1 = 0.0f, v2 = 0.0f, v3 = 0.0f;
    {
        const int cnt = bcnt[tid];                  // may exceed DEPTH
        if (cnt > 0) { k0 = bkey[tid][0]; v0 = bval[tid][0]; }
        if (cnt > 1) { k1 = bkey[tid][1]; v1 = bval[tid][1]; }
        if (cnt > 2) { k2 = bkey[tid][2]; v2 = bval[tid][2]; }
        if (cnt > 3) { k3 = bkey[tid][3]; v3 = bval[tid][3]; }
    }

    float* __restrict__ rowp = out + rb;

    // scalar head/tail (patched later by overflow atomics if targeted)
    if (tid < head)  __builtin_nontemporal_store(0.0f, rowp + tid);
    if (tid < ntail) __builtin_nontemporal_store(0.0f, rowp + head + (nvec << 2) + tid);

    // ---- Phase 2: pure-store NT stream with register compares ----
    floatx4* __restrict__ vp = (floatx4*)(rowp + head);
    #pragma unroll 2
    for (int c = tid; c < nvec; c += 256) {
        const uint32_t d0 = (uint32_t)(c << 2);
        floatx4 o;
        o.x = ((k0 == d0     ) ? v0 : 0.0f) + ((k1 == d0     ) ? v1 : 0.0f)
            + ((k2 == d0     ) ? v2 : 0.0f) + ((k3 == d0     ) ? v3 : 0.0f);
        o.y = ((k0 == d0 + 1u) ? v0 : 0.0f) + ((k1 == d0 + 1u) ? v1 : 0.0f)
            + ((k2 == d0 + 1u) ? v2 : 0.0f) + ((k3 == d0 + 1u) ? v3 : 0.0f);
        o.z = ((k0 == d0 + 2u) ? v0 : 0.0f) + ((k1 == d0 + 2u) ? v1 : 0.0f)
            + ((k2 == d0 + 2u) ? v2 : 0.0f) + ((k3 == d0 + 2u) ? v3 : 0.0f);
        o.w = ((k0 == d0 + 3u) ? v0 : 0.0f) + ((k1 == d0 + 3u) ? v1 : 0.0f)
            + ((k2 == d0 + 3u) ? v2 : 0.0f) + ((k3 == d0 + 3u) ? v3 : 0.0f);
        __builtin_nontemporal_store(o, vp + c);
    }

    // ---- Phase 3: overflow (barrier drains vmcnt; atomics execute at TCC) ----
    __syncthreads();
    for (int i = tid; i < ocnt; i += 256) {
        atomicAdd(rowp + okey[i], oval[i]);
    }
}

extern "C" void kernel_launch(void* const* d_in, const int* in_sizes, int n_in,
                              void* d_out, int out_size, void* d_ws, size_t ws_size,
                              hipStream_t stream) {
    const float* p_pos = (const float*)d_in[0];   // [B,T,S]
    // d_in[1] = p_target_vocab — dead data (shape-only in the reference).
    const int*   src   = (const int*)d_in[2];     // [B,S]
    float*       out   = (float*)d_out;           // [B,T,V]

    onepass_nt_kernel<<<DIM_B * DIM_T, DIM_S, 0, stream>>>(p_pos, src, out);
}

// Round 12
// 91.048 us; speedup vs baseline: 1.2558x; 1.2558x over previous
//
#include <hip/hip_runtime.h>
#include <stdint.h>

// Problem constants (from reference): B=4, T=512, S=256, V=50257.
#define DIM_B 4
#define DIM_T 512
#define DIM_S 256
#define DIM_V 50257
#define NCHUNK 25731584u   // B*T*V/4 — exact (out_size % 4 == 0)
#define NZBLK  100514u     // NCHUNK/256 — exact, so no bounds check needed
#define HSZ   512          // per-row LDS hash slots (<=256 entries -> load 0.5)
#define HMSK  (HSZ - 1)

// ---- PROBE KERNEL: exact clone of the suspected vendor-fill geometry ----
// Giant grid, ONE float4 store per thread, no loop, no bounds check (grid
// exactly tiles the buffer), ~zero VALU. Every looping store kernel we've
// built caps at <=4.65 TB/s; the vendor fill (VGPR=8, occupancy ~10.6% =
// launch-limited trivial waves) hits 6.65-6.9 TB/s. This isolates "wave-churn
// giant grid" as the last untested discriminator.
__global__ __launch_bounds__(256) void zero_clone_kernel(float4* __restrict__ out4) {
    const uint32_t g = blockIdx.x * 256u + threadIdx.x;
    out4[g] = make_float4(0.0f, 0.0f, 0.0f, 0.0f);
}

// ---- R5's proven patch kernel (34.3us incl. RMW): LDS hash dedupe + 4B stores ----
__global__ __launch_bounds__(256) void patch_kernel(
    const float* __restrict__ p_pos,   // [B, T, S]
    const int*   __restrict__ src,     // [B, S]  (int64 narrowed to int32)
    float*       __restrict__ out)     // [B, T, V]
{
    __shared__ int   hk[HSZ];
    __shared__ float hv[HSZ];

    const int row = blockIdx.x;        // row = b*T + t
    const int b   = row >> 9;          // T = 512
    const int tid = threadIdx.x;       // s index (S == blockDim.x == 256)

    for (int i = tid; i < HSZ; i += 256) { hk[i] = -1; hv[i] = 0.0f; }
    __syncthreads();

    const int   v = src[b * DIM_S + tid];
    const float p = p_pos[(size_t)row * DIM_S + tid];
    int h = v & HMSK;
    while (true) {
        const int prev = atomicCAS(&hk[h], -1, v);
        if (prev == -1 || prev == v) { atomicAdd(&hv[h], p); break; }
        h = (h + 1) & HMSK;
    }
    __syncthreads();

    float* __restrict__ row_ptr = out + (size_t)row * DIM_V;
    for (int i = tid; i < HSZ; i += 256) {
        const int k = hk[i];
        if (k >= 0) row_ptr[k] = hv[i];   // plain 4B store, unique address
    }
}

extern "C" void kernel_launch(void* const* d_in, const int* in_sizes, int n_in,
                              void* d_out, int out_size, void* d_ws, size_t ws_size,
                              hipStream_t stream) {
    const float* p_pos = (const float*)d_in[0];   // [B,T,S]
    // d_in[1] = p_target_vocab — dead data (shape-only in the reference).
    const int*   src   = (const int*)d_in[2];     // [B,S]
    float*       out   = (float*)d_out;           // [B,T,V]

    // Probe: fill-clone zero (giant grid, 1 store/thread) instead of memset.
    zero_clone_kernel<<<NZBLK, 256, 0, stream>>>((float4*)out);
    // Proven patch: scatter the deduped values on top.
    patch_kernel<<<DIM_B * DIM_T, DIM_S, 0, stream>>>(p_pos, src, out);
}